// Round 1
// baseline (1439.961 us; speedup 1.0000x reference)
//
#include <hip/hip_runtime.h>

#define B_ 256
#define S_ 512
#define V_ 50000
#define F_ 64
#define H_ 256

typedef _Float16 f16;
typedef _Float16 f16x2 __attribute__((ext_vector_type(2)));
typedef _Float16 f16x4 __attribute__((ext_vector_type(4)));
typedef _Float16 f16x8 __attribute__((ext_vector_type(8)));
typedef float f32x4 __attribute__((ext_vector_type(4)));

__device__ __forceinline__ f16x8 cvt8(const float4 a, const float4 b) {
    f16x8 v;
    v[0] = (f16)a.x; v[1] = (f16)a.y; v[2] = (f16)a.z; v[3] = (f16)a.w;
    v[4] = (f16)b.x; v[5] = (f16)b.y; v[6] = (f16)b.z; v[7] = (f16)b.w;
    return v;
}

__device__ __forceinline__ float fast_tanh(float x) {
    x = fminf(15.f, fmaxf(-15.f, x));
    float e = __expf(2.f * x);                       // v_exp path
    float r = __builtin_amdgcn_rcpf(e + 1.f);        // ~1 ulp, fine
    return __builtin_fmaf(-2.f, r, 1.f);             // 1 - 2/(e^2x+1)
}

// ---------------------------------------------------------------------------
// K1: T[v][n] = sum_f feat[v][f] * Wih0[n][f] + (bi[n]+bh[n]); f16 out.
// Swapped-operand MFMA: D[n][m=v], A = W rows, B = feat rows.
// ---------------------------------------------------------------------------
__global__ __launch_bounds__(512) void k_vocab_proj(
    const float* __restrict__ feat, const float* __restrict__ Wih,
    const float* __restrict__ bi, const float* __restrict__ bh,
    f16* __restrict__ T)
{
    __shared__ char Wl[256 * 128];   // [256 n][64 f16 = 128B] swizzled
    __shared__ char Xl[16 * 128];    // [16 v][128B] swizzled
    const int tid = threadIdx.x;
    {
        const int n = tid >> 1, k0 = (tid & 1) << 5;
#pragma unroll
        for (int k = k0; k < k0 + 32; k += 8) {
            float4 a = *(const float4*)(Wih + n * F_ + k);
            float4 b = *(const float4*)(Wih + n * F_ + k + 4);
            *(f16x8*)(Wl + n * 128 + (((k >> 3) ^ (n & 7)) << 4)) = cvt8(a, b);
        }
    }
    const int v0 = blockIdx.x * 16;
    {
        const int m = tid >> 5, k = (tid & 31) << 1;
        float2 a = *(const float2*)(feat + (v0 + m) * F_ + k);
        f16x2 v; v[0] = (f16)a.x; v[1] = (f16)a.y;
        *(f16x2*)(Xl + m * 128 + ((((k >> 3) ^ (m & 7)) << 4) | ((k & 7) << 1))) = v;
    }
    __syncthreads();
    const int lane = tid & 63, w = tid >> 6;
    const int q = lane & 15, g = lane >> 4;
#pragma unroll
    for (int nt = 0; nt < 2; ++nt) {
        const int n0 = w * 32 + nt * 16;
        const int nrow = n0 + q;
        float4 b1 = *(const float4*)(bi + n0 + g * 4);
        float4 b2 = *(const float4*)(bh + n0 + g * 4);
        f32x4 acc = {b1.x + b2.x, b1.y + b2.y, b1.z + b2.z, b1.w + b2.w};
#pragma unroll
        for (int kb = 0; kb < 2; ++kb) {
            f16x8 a = *(const f16x8*)(Wl + nrow * 128 + (((kb * 4 + g) ^ (nrow & 7)) << 4));
            f16x8 b = *(const f16x8*)(Xl + q * 128 + (((kb * 4 + g) ^ (q & 7)) << 4));
            acc = __builtin_amdgcn_mfma_f32_16x16x32_f16(a, b, acc, 0, 0, 0);
        }
        f16x4 o; o[0] = (f16)acc[0]; o[1] = (f16)acc[1]; o[2] = (f16)acc[2]; o[3] = (f16)acc[3];
        *(f16x4*)(T + (size_t)(v0 + q) * H_ + n0 + g * 4) = o;
    }
}

// ---------------------------------------------------------------------------
// K2/K4: RNN recurrence, 16 WGs x 256 threads (4 waves), 16 batches/WG.
// W_hh held in VGPRs (4 n-tiles x 8 k-blocks of f16x8 per lane = 128 VGPR).
// h exchanged per step through 8KB XOR-swizzled LDS.
// GATHER: xw = T[V][H], row via idx; else xw = [B][S][H].
// WRITE_ALL: store h every step; else only final step -> hout[B][H].
// ---------------------------------------------------------------------------
template <bool GATHER, bool WRITE_ALL>
__global__ __launch_bounds__(256, 1) void k_recur(
    const f16* __restrict__ xw, const int* __restrict__ idx,
    const float* __restrict__ Whh, f16* __restrict__ hout)
{
    __shared__ char hbuf[16 * 512];  // [16 m][256 n f16] swizzled
    const int tid = threadIdx.x, lane = tid & 63, w = tid >> 6;
    const int q = lane & 15, g = lane >> 4;
    const int b0 = blockIdx.x << 4;
    const int brow = b0 + q;

    f16x8 wf[4][8];
#pragma unroll
    for (int tt = 0; tt < 4; ++tt) {
        const int n = w * 64 + tt * 16 + q;
#pragma unroll
        for (int kb = 0; kb < 8; ++kb) {
            float4 a = *(const float4*)(Whh + n * H_ + kb * 32 + g * 8);
            float4 b = *(const float4*)(Whh + n * H_ + kb * 32 + g * 8 + 4);
            wf[tt][kb] = cvt8(a, b);
        }
    }
    {
        f32x4 z = {0.f, 0.f, 0.f, 0.f};
        *(f32x4*)(hbuf + tid * 32) = z;
        *(f32x4*)(hbuf + tid * 32 + 16) = z;
    }
    __syncthreads();

    const int hswz = (q & 7) << 4;
    const int hrow = q * 512;

    f16x4 xcur[4], xnxt[4];
    int id_nxt = 0;
    if (GATHER) {
        int id0 = idx[brow * S_];
#pragma unroll
        for (int tt = 0; tt < 4; ++tt)
            xcur[tt] = *(const f16x4*)(xw + (size_t)id0 * H_ + w * 64 + tt * 16 + g * 4);
        id_nxt = idx[brow * S_ + 1];
    } else {
#pragma unroll
        for (int tt = 0; tt < 4; ++tt)
            xcur[tt] = *(const f16x4*)(xw + (size_t)brow * S_ * H_ + w * 64 + tt * 16 + g * 4);
    }

    for (int t = 0; t < S_; ++t) {
        if (t + 1 < S_) {   // prefetch next step's xw row (2-deep idx->row pipeline)
            const size_t rb = GATHER ? (size_t)id_nxt * H_ : ((size_t)brow * S_ + t + 1) * H_;
#pragma unroll
            for (int tt = 0; tt < 4; ++tt)
                xnxt[tt] = *(const f16x4*)(xw + rb + w * 64 + tt * 16 + g * 4);
            if (GATHER && (t + 2 < S_)) id_nxt = idx[brow * S_ + t + 2];
        }
        f32x4 acc[4];
#pragma unroll
        for (int tt = 0; tt < 4; ++tt) {
            acc[tt][0] = (float)xcur[tt][0]; acc[tt][1] = (float)xcur[tt][1];
            acc[tt][2] = (float)xcur[tt][2]; acc[tt][3] = (float)xcur[tt][3];
        }
#pragma unroll
        for (int kb = 0; kb < 8; ++kb) {
            f16x8 bf = *(const f16x8*)(hbuf + hrow + ((kb * 64 + g * 16) ^ hswz));
#pragma unroll
            for (int tt = 0; tt < 4; ++tt)
                acc[tt] = __builtin_amdgcn_mfma_f32_16x16x32_f16(wf[tt][kb], bf, acc[tt], 0, 0, 0);
        }
        f16x4 hv[4];
#pragma unroll
        for (int tt = 0; tt < 4; ++tt) {
#pragma unroll
            for (int r = 0; r < 4; ++r)
                hv[tt][r] = (f16)fast_tanh(acc[tt][r]);
        }
        __syncthreads();   // all reads of h_{t-1} complete
#pragma unroll
        for (int tt = 0; tt < 4; ++tt) {
            const int nd = w * 64 + tt * 16 + g * 4;
            *(f16x4*)(hbuf + hrow + ((nd * 2) ^ hswz)) = hv[tt];
        }
        if (WRITE_ALL) {
#pragma unroll
            for (int tt = 0; tt < 4; ++tt) {
                const int nd = w * 64 + tt * 16 + g * 4;
                *(f16x4*)(hout + ((size_t)brow * S_ + t) * H_ + nd) = hv[tt];
            }
        } else if (t == S_ - 1) {
#pragma unroll
            for (int tt = 0; tt < 4; ++tt) {
                const int nd = w * 64 + tt * 16 + g * 4;
                *(f16x4*)(hout + (size_t)brow * H_ + nd) = hv[tt];
            }
        }
        __syncthreads();   // h_t visible for next step
#pragma unroll
        for (int tt = 0; tt < 4; ++tt) xcur[tt] = xnxt[tt];
    }
}

// ---------------------------------------------------------------------------
// K3: xW1 = h0 @ Wih1^T + (bi+bh), IN PLACE over h0 buffer. [131072 x 256] x [256 x 256]
// ---------------------------------------------------------------------------
__global__ __launch_bounds__(512) void k_proj1(
    f16* __restrict__ h0, const float* __restrict__ Wih,
    const float* __restrict__ bi, const float* __restrict__ bh)
{
    __shared__ char Wl[256 * 512];   // 128KB: [256 n][256 f16] swizzled
    __shared__ char Al[32 * 512];    // 16KB: staged h0 rows
    const int tid = threadIdx.x;
    {
        const int n = tid >> 1, k0 = (tid & 1) << 7;
#pragma unroll
        for (int k = k0; k < k0 + 128; k += 8) {
            float4 a = *(const float4*)(Wih + n * H_ + k);
            float4 b = *(const float4*)(Wih + n * H_ + k + 4);
            *(f16x8*)(Wl + n * 512 + (((k >> 3) ^ (n & 7)) << 4)) = cvt8(a, b);
        }
    }
    const int lane = tid & 63, w = tid >> 6;
    const int q = lane & 15, g = lane >> 4;
    for (int rb = blockIdx.x; rb < (B_ * S_) / 32; rb += gridDim.x) {
        const size_t r0 = (size_t)rb * 32;
        __syncthreads();   // W staged (iter 0) / prior iter's Al reads done
        {
            const int m = tid >> 4, blk0 = (tid & 15) << 1;
#pragma unroll
            for (int i = 0; i < 2; ++i) {
                const int blk = blk0 + i;
                f16x8 v = *(const f16x8*)(h0 + (r0 + m) * H_ + blk * 8);
                *(f16x8*)(Al + m * 512 + ((blk ^ (m & 7)) << 4)) = v;
            }
        }
        __syncthreads();
        f32x4 acc[2][2];
#pragma unroll
        for (int nt = 0; nt < 2; ++nt) {
            const int nb = w * 32 + nt * 16 + g * 4;
            float4 b1 = *(const float4*)(bi + nb);
            float4 b2 = *(const float4*)(bh + nb);
#pragma unroll
            for (int mt = 0; mt < 2; ++mt) {
                acc[nt][mt][0] = b1.x + b2.x; acc[nt][mt][1] = b1.y + b2.y;
                acc[nt][mt][2] = b1.z + b2.z; acc[nt][mt][3] = b1.w + b2.w;
            }
        }
#pragma unroll
        for (int kb = 0; kb < 8; ++kb) {
            f16x8 af[2], bf[2];
#pragma unroll
            for (int nt = 0; nt < 2; ++nt) {
                const int nrow = w * 32 + nt * 16 + q;
                af[nt] = *(const f16x8*)(Wl + nrow * 512 + (((kb * 4 + g) ^ (nrow & 7)) << 4));
            }
#pragma unroll
            for (int mt = 0; mt < 2; ++mt) {
                const int mrow = mt * 16 + q;
                bf[mt] = *(const f16x8*)(Al + mrow * 512 + (((kb * 4 + g) ^ (mrow & 7)) << 4));
            }
#pragma unroll
            for (int nt = 0; nt < 2; ++nt)
#pragma unroll
                for (int mt = 0; mt < 2; ++mt)
                    acc[nt][mt] = __builtin_amdgcn_mfma_f32_16x16x32_f16(af[nt], bf[mt], acc[nt][mt], 0, 0, 0);
        }
#pragma unroll
        for (int nt = 0; nt < 2; ++nt) {
            const int nb = w * 32 + nt * 16 + g * 4;
#pragma unroll
            for (int mt = 0; mt < 2; ++mt) {
                f16x4 o;
                o[0] = (f16)acc[nt][mt][0]; o[1] = (f16)acc[nt][mt][1];
                o[2] = (f16)acc[nt][mt][2]; o[3] = (f16)acc[nt][mt][3];
                *(f16x4*)(h0 + (r0 + mt * 16 + q) * H_ + nb) = o;
            }
        }
    }
}

// ---------------------------------------------------------------------------
// K5: out[b][v] = sum_k h1[b][k] * Wout[v][k] + bout[v].  fp32 out.
// 625 blocks x 80 v each (50000 = 625*80). h1 staged to 128KB swizzled LDS.
// ---------------------------------------------------------------------------
__global__ __launch_bounds__(512) void k_out(
    const f16* __restrict__ h1, const float* __restrict__ Wout,
    const float* __restrict__ bout, float* __restrict__ out)
{
    __shared__ char Hl[256 * 512];
    const int tid = threadIdx.x;
    {
        const int m = tid >> 1, half = tid & 1;
#pragma unroll
        for (int i = 0; i < 16; ++i) {
            const int blk = half * 16 + i;
            f16x8 v = *(const f16x8*)(h1 + m * H_ + blk * 8);
            *(f16x8*)(Hl + m * 512 + ((blk ^ (m & 7)) << 4)) = v;
        }
    }
    __syncthreads();
    const int lane = tid & 63, w = tid >> 6;
    const int q = lane & 15, g = lane >> 4;
    const int v0 = blockIdx.x * 80;
    f32x4 acc[5][2];
#pragma unroll
    for (int vt = 0; vt < 5; ++vt) {
        float4 bo = *(const float4*)(bout + v0 + vt * 16 + g * 4);
#pragma unroll
        for (int bt = 0; bt < 2; ++bt) {
            acc[vt][bt][0] = bo.x; acc[vt][bt][1] = bo.y;
            acc[vt][bt][2] = bo.z; acc[vt][bt][3] = bo.w;
        }
    }
#pragma unroll
    for (int kb = 0; kb < 8; ++kb) {
        f16x8 bf[2];
#pragma unroll
        for (int bt = 0; bt < 2; ++bt) {
            const int mrow = (w * 2 + bt) * 16 + q;
            bf[bt] = *(const f16x8*)(Hl + mrow * 512 + (((kb * 4 + g) ^ (mrow & 7)) << 4));
        }
#pragma unroll
        for (int vt = 0; vt < 5; ++vt) {
            const size_t vrow = v0 + vt * 16 + q;
            float4 a = *(const float4*)(Wout + vrow * H_ + kb * 32 + g * 8);
            float4 b = *(const float4*)(Wout + vrow * H_ + kb * 32 + g * 8 + 4);
            f16x8 af = cvt8(a, b);
#pragma unroll
            for (int bt = 0; bt < 2; ++bt)
                acc[vt][bt] = __builtin_amdgcn_mfma_f32_16x16x32_f16(af, bf[bt], acc[vt][bt], 0, 0, 0);
        }
    }
#pragma unroll
    for (int vt = 0; vt < 5; ++vt)
#pragma unroll
        for (int bt = 0; bt < 2; ++bt) {
            const int b = (w * 2 + bt) * 16 + q;
            const int v = v0 + vt * 16 + g * 4;
            float4 o = {acc[vt][bt][0], acc[vt][bt][1], acc[vt][bt][2], acc[vt][bt][3]};
            *(float4*)(out + (size_t)b * V_ + v) = o;
        }
}

extern "C" void kernel_launch(void* const* d_in, const int* in_sizes, int n_in,
                              void* d_out, int out_size, void* d_ws, size_t ws_size,
                              hipStream_t stream) {
    (void)in_sizes; (void)n_in; (void)out_size; (void)ws_size;
    const int*   batch = (const int*)  d_in[0];
    const float* feat  = (const float*)d_in[1];
    const float* Wih0  = (const float*)d_in[2];
    const float* Whh0  = (const float*)d_in[3];
    const float* bih0  = (const float*)d_in[4];
    const float* bhh0  = (const float*)d_in[5];
    const float* Wih1  = (const float*)d_in[6];
    const float* Whh1  = (const float*)d_in[7];
    const float* bih1  = (const float*)d_in[8];
    const float* bhh1  = (const float*)d_in[9];
    const float* Wout  = (const float*)d_in[10];
    const float* bout  = (const float*)d_in[11];
    float* out = (float*)d_out;

    f16* T  = (f16*)d_out;                               // 25.6MB, dead before K5 writes
    f16* h0 = (f16*)d_ws;                                // 67MB: h0 then xW1 (in place)
    f16* h1 = (f16*)((char*)d_ws + (size_t)B_ * S_ * H_ * 2);

    k_vocab_proj<<<dim3(V_ / 16), dim3(512), 0, stream>>>(feat, Wih0, bih0, bhh0, T);
    k_recur<true, true><<<dim3(16), dim3(256), 0, stream>>>(T, batch, Whh0, h0);
    k_proj1<<<dim3(512), dim3(512), 0, stream>>>(h0, Wih1, bih1, bhh1);
    k_recur<false, false><<<dim3(16), dim3(256), 0, stream>>>(h0, nullptr, Whh1, h1);
    k_out<<<dim3(625), dim3(512), 0, stream>>>(h1, Wout, bout, out);
}

// Round 2
// 1228.338 us; speedup vs baseline: 1.1723x; 1.1723x over previous
//
#include <hip/hip_runtime.h>

#define B_ 256
#define S_ 512
#define V_ 50000
#define F_ 64
#define H_ 256

typedef _Float16 f16;
typedef _Float16 f16x2 __attribute__((ext_vector_type(2)));
typedef _Float16 f16x4 __attribute__((ext_vector_type(4)));
typedef _Float16 f16x8 __attribute__((ext_vector_type(8)));
typedef float f32x4 __attribute__((ext_vector_type(4)));

__device__ __forceinline__ f16x8 cvt8(const float4 a, const float4 b) {
    f16x8 v;
    v[0] = (f16)a.x; v[1] = (f16)a.y; v[2] = (f16)a.z; v[3] = (f16)a.w;
    v[4] = (f16)b.x; v[5] = (f16)b.y; v[6] = (f16)b.z; v[7] = (f16)b.w;
    return v;
}

// tanh(x) = 1 - 2/(1+e^2x). No clamp needed: x->+inf gives e=inf, rcp=0, ->1;
// x->-inf gives e=0, rcp(1)=1, ->-1. 3 VALU + 2 trans per value.
__device__ __forceinline__ float fast_tanh(float x) {
    float e = __expf(2.f * x);
    float r = __builtin_amdgcn_rcpf(e + 1.f);
    return __builtin_fmaf(-2.f, r, 1.f);
}

// ---------------------------------------------------------------------------
// K1: T[v][n] = sum_f feat[v][f] * Wih0[n][f] + (bi[n]+bh[n]); f16 out.
// ---------------------------------------------------------------------------
__global__ __launch_bounds__(512) void k_vocab_proj(
    const float* __restrict__ feat, const float* __restrict__ Wih,
    const float* __restrict__ bi, const float* __restrict__ bh,
    f16* __restrict__ T)
{
    __shared__ char Wl[256 * 128];   // [256 n][64 f16 = 128B] swizzled
    __shared__ char Xl[16 * 128];    // [16 v][128B] swizzled
    const int tid = threadIdx.x;
    {
        const int n = tid >> 1, k0 = (tid & 1) << 5;
#pragma unroll
        for (int k = k0; k < k0 + 32; k += 8) {
            float4 a = *(const float4*)(Wih + n * F_ + k);
            float4 b = *(const float4*)(Wih + n * F_ + k + 4);
            *(f16x8*)(Wl + n * 128 + (((k >> 3) ^ (n & 7)) << 4)) = cvt8(a, b);
        }
    }
    const int v0 = blockIdx.x * 16;
    {
        const int m = tid >> 5, k = (tid & 31) << 1;
        float2 a = *(const float2*)(feat + (v0 + m) * F_ + k);
        f16x2 v; v[0] = (f16)a.x; v[1] = (f16)a.y;
        *(f16x2*)(Xl + m * 128 + ((((k >> 3) ^ (m & 7)) << 4) | ((k & 7) << 1))) = v;
    }
    __syncthreads();
    const int lane = tid & 63, w = tid >> 6;
    const int q = lane & 15, g = lane >> 4;
#pragma unroll
    for (int nt = 0; nt < 2; ++nt) {
        const int n0 = w * 32 + nt * 16;
        const int nrow = n0 + q;
        float4 b1 = *(const float4*)(bi + n0 + g * 4);
        float4 b2 = *(const float4*)(bh + n0 + g * 4);
        f32x4 acc = {b1.x + b2.x, b1.y + b2.y, b1.z + b2.z, b1.w + b2.w};
#pragma unroll
        for (int kb = 0; kb < 2; ++kb) {
            f16x8 a = *(const f16x8*)(Wl + nrow * 128 + (((kb * 4 + g) ^ (nrow & 7)) << 4));
            f16x8 b = *(const f16x8*)(Xl + q * 128 + (((kb * 4 + g) ^ (q & 7)) << 4));
            acc = __builtin_amdgcn_mfma_f32_16x16x32_f16(a, b, acc, 0, 0, 0);
        }
        f16x4 o; o[0] = (f16)acc[0]; o[1] = (f16)acc[1]; o[2] = (f16)acc[2]; o[3] = (f16)acc[3];
        *(f16x4*)(T + (size_t)(v0 + q) * H_ + n0 + g * 4) = o;
    }
}

// ---------------------------------------------------------------------------
// K2/K4: RNN recurrence. 16 WGs x 256 thr. W_hh in regs (wf), h double-
// buffered in LDS, ONE raw barrier per step with lgkm-only wait (global
// prefetch loads + hout stores stay in flight across steps), 2-deep
// prefetch via anti-dependency reload (consume xv, then overwrite xv with
// the row for t+2; unroll-2 over register sets xa/xb).
// ---------------------------------------------------------------------------
template <bool GATHER, bool WRITE_ALL>
__device__ __forceinline__ void rnn_step(
    const int t, const f16* __restrict__ xw, const int* __restrict__ idx,
    f16* __restrict__ hout, const f16x8 (&wf)[4][8],
    f16x4 (&xv)[4], int& id_n2,
    const char* __restrict__ rbuf, char* __restrict__ wbuf,
    const int brow, const int ncol, const int g, const int hrow, const int hswz)
{
    // consume xv (load issued 2 steps ago -> auto vmcnt wait lands here)
    f32x4 acc[4];
#pragma unroll
    for (int tt = 0; tt < 4; ++tt) {
        acc[tt][0] = (float)xv[tt][0]; acc[tt][1] = (float)xv[tt][1];
        acc[tt][2] = (float)xv[tt][2]; acc[tt][3] = (float)xv[tt][3];
    }
    // reissue into the same registers for step t+2 (anti-dep, no copy)
    if (t + 2 < S_) {
        const size_t rb2 = GATHER ? (size_t)id_n2 * H_ : ((size_t)brow * S_ + t + 2) * H_;
#pragma unroll
        for (int tt = 0; tt < 4; ++tt)
            xv[tt] = *(const f16x4*)(xw + rb2 + ncol + tt * 16 + g * 4);
        if (GATHER && (t + 3 < S_)) id_n2 = idx[brow * S_ + t + 3];
    }
#pragma unroll
    for (int kb = 0; kb < 8; ++kb) {
        f16x8 bf = *(const f16x8*)(rbuf + hrow + ((kb * 64 + g * 16) ^ hswz));
#pragma unroll
        for (int tt = 0; tt < 4; ++tt)
            acc[tt] = __builtin_amdgcn_mfma_f32_16x16x32_f16(wf[tt][kb], bf, acc[tt], 0, 0, 0);
    }
    f16x4 hv[4];
#pragma unroll
    for (int tt = 0; tt < 4; ++tt) {
#pragma unroll
        for (int r = 0; r < 4; ++r)
            hv[tt][r] = (f16)fast_tanh(acc[tt][r]);
    }
#pragma unroll
    for (int tt = 0; tt < 4; ++tt) {
        const int nd = ncol + tt * 16 + g * 4;
        *(f16x4*)(wbuf + hrow + ((nd * 2) ^ hswz)) = hv[tt];
    }
    if (WRITE_ALL) {
#pragma unroll
        for (int tt = 0; tt < 4; ++tt)
            *(f16x4*)(hout + ((size_t)brow * S_ + t) * H_ + ncol + tt * 16 + g * 4) = hv[tt];
    } else if (t == S_ - 1) {
#pragma unroll
        for (int tt = 0; tt < 4; ++tt)
            *(f16x4*)(hout + (size_t)brow * H_ + ncol + tt * 16 + g * 4) = hv[tt];
    }
    // LDS-only fence + raw barrier: do NOT drain vmcnt (prefetch/stores fly on)
    asm volatile("s_waitcnt lgkmcnt(0)\n\ts_barrier" ::: "memory");
}

template <bool GATHER, bool WRITE_ALL>
__global__ __launch_bounds__(256, 1) void k_recur(
    const f16* __restrict__ xw, const int* __restrict__ idx,
    const float* __restrict__ Whh, f16* __restrict__ hout)
{
    __shared__ char hbuf[2][16 * 512];  // double-buffered [16 m][256 n f16], swizzled
    const int tid = threadIdx.x, lane = tid & 63, w = tid >> 6;
    const int q = lane & 15, g = lane >> 4;
    const int brow = (blockIdx.x << 4) + q;
    const int ncol = w * 64;

    f16x8 wf[4][8];
#pragma unroll
    for (int tt = 0; tt < 4; ++tt) {
        const int n = ncol + tt * 16 + q;
#pragma unroll
        for (int kb = 0; kb < 8; ++kb) {
            float4 a = *(const float4*)(Whh + n * H_ + kb * 32 + g * 8);
            float4 b = *(const float4*)(Whh + n * H_ + kb * 32 + g * 8 + 4);
            wf[tt][kb] = cvt8(a, b);
        }
    }
    {   // h_{-1} = 0 into buf[1] (read buffer of step 0)
        f32x4 z = {0.f, 0.f, 0.f, 0.f};
        *(f32x4*)(hbuf[1] + tid * 32) = z;
        *(f32x4*)(hbuf[1] + tid * 32 + 16) = z;
    }
    const int hswz = (q & 7) << 4;
    const int hrow = q * 512;

    f16x4 xa[4], xb[4];
    int id_n2 = 0;
    {
        size_t r0, r1;
        if (GATHER) {
            r0 = (size_t)idx[brow * S_] * H_;
            r1 = (size_t)idx[brow * S_ + 1] * H_;
            id_n2 = idx[brow * S_ + 2];
        } else {
            r0 = (size_t)brow * S_ * H_;
            r1 = r0 + H_;
        }
#pragma unroll
        for (int tt = 0; tt < 4; ++tt) {
            xa[tt] = *(const f16x4*)(xw + r0 + ncol + tt * 16 + g * 4);
            xb[tt] = *(const f16x4*)(xw + r1 + ncol + tt * 16 + g * 4);
        }
    }
    __syncthreads();   // once: zero-init + W visible

    for (int t = 0; t < S_; t += 2) {
        rnn_step<GATHER, WRITE_ALL>(t,     xw, idx, hout, wf, xa, id_n2,
                                    hbuf[1], hbuf[0], brow, ncol, g, hrow, hswz);
        rnn_step<GATHER, WRITE_ALL>(t + 1, xw, idx, hout, wf, xb, id_n2,
                                    hbuf[0], hbuf[1], brow, ncol, g, hrow, hswz);
    }
}

// ---------------------------------------------------------------------------
// K3: xW1 = h0 @ Wih1^T + (bi+bh), IN PLACE over h0 buffer.
// ---------------------------------------------------------------------------
__global__ __launch_bounds__(512) void k_proj1(
    f16* __restrict__ h0, const float* __restrict__ Wih,
    const float* __restrict__ bi, const float* __restrict__ bh)
{
    __shared__ char Wl[256 * 512];   // 128KB: [256 n][256 f16] swizzled
    __shared__ char Al[32 * 512];    // 16KB: staged h0 rows
    const int tid = threadIdx.x;
    {
        const int n = tid >> 1, k0 = (tid & 1) << 7;
#pragma unroll
        for (int k = k0; k < k0 + 128; k += 8) {
            float4 a = *(const float4*)(Wih + n * H_ + k);
            float4 b = *(const float4*)(Wih + n * H_ + k + 4);
            *(f16x8*)(Wl + n * 512 + (((k >> 3) ^ (n & 7)) << 4)) = cvt8(a, b);
        }
    }
    const int lane = tid & 63, w = tid >> 6;
    const int q = lane & 15, g = lane >> 4;
    for (int rb = blockIdx.x; rb < (B_ * S_) / 32; rb += gridDim.x) {
        const size_t r0 = (size_t)rb * 32;
        __syncthreads();
        {
            const int m = tid >> 4, blk0 = (tid & 15) << 1;
#pragma unroll
            for (int i = 0; i < 2; ++i) {
                const int blk = blk0 + i;
                f16x8 v = *(const f16x8*)(h0 + (r0 + m) * H_ + blk * 8);
                *(f16x8*)(Al + m * 512 + ((blk ^ (m & 7)) << 4)) = v;
            }
        }
        __syncthreads();
        f32x4 acc[2][2];
#pragma unroll
        for (int nt = 0; nt < 2; ++nt) {
            const int nb = w * 32 + nt * 16 + g * 4;
            float4 b1 = *(const float4*)(bi + nb);
            float4 b2 = *(const float4*)(bh + nb);
#pragma unroll
            for (int mt = 0; mt < 2; ++mt) {
                acc[nt][mt][0] = b1.x + b2.x; acc[nt][mt][1] = b1.y + b2.y;
                acc[nt][mt][2] = b1.z + b2.z; acc[nt][mt][3] = b1.w + b2.w;
            }
        }
#pragma unroll
        for (int kb = 0; kb < 8; ++kb) {
            f16x8 af[2], bf[2];
#pragma unroll
            for (int nt = 0; nt < 2; ++nt) {
                const int nrow = w * 32 + nt * 16 + q;
                af[nt] = *(const f16x8*)(Wl + nrow * 512 + (((kb * 4 + g) ^ (nrow & 7)) << 4));
            }
#pragma unroll
            for (int mt = 0; mt < 2; ++mt) {
                const int mrow = mt * 16 + q;
                bf[mt] = *(const f16x8*)(Al + mrow * 512 + (((kb * 4 + g) ^ (mrow & 7)) << 4));
            }
#pragma unroll
            for (int nt = 0; nt < 2; ++nt)
#pragma unroll
                for (int mt = 0; mt < 2; ++mt)
                    acc[nt][mt] = __builtin_amdgcn_mfma_f32_16x16x32_f16(af[nt], bf[mt], acc[nt][mt], 0, 0, 0);
        }
#pragma unroll
        for (int nt = 0; nt < 2; ++nt) {
            const int nb = w * 32 + nt * 16 + g * 4;
#pragma unroll
            for (int mt = 0; mt < 2; ++mt) {
                f16x4 o;
                o[0] = (f16)acc[nt][mt][0]; o[1] = (f16)acc[nt][mt][1];
                o[2] = (f16)acc[nt][mt][2]; o[3] = (f16)acc[nt][mt][3];
                *(f16x4*)(h0 + (r0 + mt * 16 + q) * H_ + nb) = o;
            }
        }
    }
}

// ---------------------------------------------------------------------------
// K5: out[b][v] = sum_k h1[b][k] * Wout[v][k] + bout[v].  fp32 out.
// ---------------------------------------------------------------------------
__global__ __launch_bounds__(512) void k_out(
    const f16* __restrict__ h1, const float* __restrict__ Wout,
    const float* __restrict__ bout, float* __restrict__ out)
{
    __shared__ char Hl[256 * 512];
    const int tid = threadIdx.x;
    {
        const int m = tid >> 1, half = tid & 1;
#pragma unroll
        for (int i = 0; i < 16; ++i) {
            const int blk = half * 16 + i;
            f16x8 v = *(const f16x8*)(h1 + m * H_ + blk * 8);
            *(f16x8*)(Hl + m * 512 + ((blk ^ (m & 7)) << 4)) = v;
        }
    }
    __syncthreads();
    const int lane = tid & 63, w = tid >> 6;
    const int q = lane & 15, g = lane >> 4;
    const int v0 = blockIdx.x * 80;
    f32x4 acc[5][2];
#pragma unroll
    for (int vt = 0; vt < 5; ++vt) {
        float4 bo = *(const float4*)(bout + v0 + vt * 16 + g * 4);
#pragma unroll
        for (int bt = 0; bt < 2; ++bt) {
            acc[vt][bt][0] = bo.x; acc[vt][bt][1] = bo.y;
            acc[vt][bt][2] = bo.z; acc[vt][bt][3] = bo.w;
        }
    }
#pragma unroll
    for (int kb = 0; kb < 8; ++kb) {
        f16x8 bf[2];
#pragma unroll
        for (int bt = 0; bt < 2; ++bt) {
            const int mrow = (w * 2 + bt) * 16 + q;
            bf[bt] = *(const f16x8*)(Hl + mrow * 512 + (((kb * 4 + g) ^ (mrow & 7)) << 4));
        }
#pragma unroll
        for (int vt = 0; vt < 5; ++vt) {
            const size_t vrow = v0 + vt * 16 + q;
            float4 a = *(const float4*)(Wout + vrow * H_ + kb * 32 + g * 8);
            float4 b = *(const float4*)(Wout + vrow * H_ + kb * 32 + g * 8 + 4);
            f16x8 af = cvt8(a, b);
#pragma unroll
            for (int bt = 0; bt < 2; ++bt)
                acc[vt][bt] = __builtin_amdgcn_mfma_f32_16x16x32_f16(af, bf[bt], acc[vt][bt], 0, 0, 0);
        }
    }
#pragma unroll
    for (int vt = 0; vt < 5; ++vt)
#pragma unroll
        for (int bt = 0; bt < 2; ++bt) {
            const int b = (w * 2 + bt) * 16 + q;
            const int v = v0 + vt * 16 + g * 4;
            float4 o = {acc[vt][bt][0], acc[vt][bt][1], acc[vt][bt][2], acc[vt][bt][3]};
            *(float4*)(out + (size_t)b * V_ + v) = o;
        }
}

extern "C" void kernel_launch(void* const* d_in, const int* in_sizes, int n_in,
                              void* d_out, int out_size, void* d_ws, size_t ws_size,
                              hipStream_t stream) {
    (void)in_sizes; (void)n_in; (void)out_size; (void)ws_size;
    const int*   batch = (const int*)  d_in[0];
    const float* feat  = (const float*)d_in[1];
    const float* Wih0  = (const float*)d_in[2];
    const float* Whh0  = (const float*)d_in[3];
    const float* bih0  = (const float*)d_in[4];
    const float* bhh0  = (const float*)d_in[5];
    const float* Wih1  = (const float*)d_in[6];
    const float* Whh1  = (const float*)d_in[7];
    const float* bih1  = (const float*)d_in[8];
    const float* bhh1  = (const float*)d_in[9];
    const float* Wout  = (const float*)d_in[10];
    const float* bout  = (const float*)d_in[11];
    float* out = (float*)d_out;

    f16* T  = (f16*)d_out;                               // 25.6MB, dead before K5 writes
    f16* h0 = (f16*)d_ws;                                // 67MB: h0 then xW1 (in place)
    f16* h1 = (f16*)((char*)d_ws + (size_t)B_ * S_ * H_ * 2);

    k_vocab_proj<<<dim3(V_ / 16), dim3(512), 0, stream>>>(feat, Wih0, bih0, bhh0, T);
    k_recur<true, true><<<dim3(16), dim3(256), 0, stream>>>(T, batch, Whh0, h0);
    k_proj1<<<dim3(512), dim3(512), 0, stream>>>(h0, Wih1, bih1, bhh1);
    k_recur<false, false><<<dim3(16), dim3(256), 0, stream>>>(h0, nullptr, Whh1, h1);
    k_out<<<dim3(625), dim3(512), 0, stream>>>(h1, Wout, bout, out);
}

// Round 3
// 948.480 us; speedup vs baseline: 1.5182x; 1.2951x over previous
//
#include <hip/hip_runtime.h>

#define B_ 256
#define S_ 512
#define V_ 50000
#define F_ 64
#define H_ 256

typedef _Float16 f16;
typedef _Float16 f16x2 __attribute__((ext_vector_type(2)));
typedef _Float16 f16x4 __attribute__((ext_vector_type(4)));
typedef _Float16 f16x8 __attribute__((ext_vector_type(8)));
typedef float f32x4 __attribute__((ext_vector_type(4)));

__device__ __forceinline__ f16x8 cvt8(const float4 a, const float4 b) {
    f16x8 v;
    v[0] = (f16)a.x; v[1] = (f16)a.y; v[2] = (f16)a.z; v[3] = (f16)a.w;
    v[4] = (f16)b.x; v[5] = (f16)b.y; v[6] = (f16)b.z; v[7] = (f16)b.w;
    return v;
}

// tanh(x) = 1 - 2/(1+e^2x); IEEE-safe at +/-inf, no clamp needed.
__device__ __forceinline__ float fast_tanh(float x) {
    float e = __expf(2.f * x);
    float r = __builtin_amdgcn_rcpf(e + 1.f);
    return __builtin_fmaf(-2.f, r, 1.f);
}

// ---------------------------------------------------------------------------
// K1: T[v][n] = sum_f feat[v][f] * Wih0[n][f] + (bi[n]+bh[n]); f16 out.
// ---------------------------------------------------------------------------
__global__ __launch_bounds__(512) void k_vocab_proj(
    const float* __restrict__ feat, const float* __restrict__ Wih,
    const float* __restrict__ bi, const float* __restrict__ bh,
    f16* __restrict__ T)
{
    __shared__ char Wl[256 * 128];   // [256 n][64 f16 = 128B] swizzled
    __shared__ char Xl[16 * 128];    // [16 v][128B] swizzled
    const int tid = threadIdx.x;
    {
        const int n = tid >> 1, k0 = (tid & 1) << 5;
#pragma unroll
        for (int k = k0; k < k0 + 32; k += 8) {
            float4 a = *(const float4*)(Wih + n * F_ + k);
            float4 b = *(const float4*)(Wih + n * F_ + k + 4);
            *(f16x8*)(Wl + n * 128 + (((k >> 3) ^ (n & 7)) << 4)) = cvt8(a, b);
        }
    }
    const int v0 = blockIdx.x * 16;
    {
        const int m = tid >> 5, k = (tid & 31) << 1;
        float2 a = *(const float2*)(feat + (v0 + m) * F_ + k);
        f16x2 v; v[0] = (f16)a.x; v[1] = (f16)a.y;
        *(f16x2*)(Xl + m * 128 + ((((k >> 3) ^ (m & 7)) << 4) | ((k & 7) << 1))) = v;
    }
    __syncthreads();
    const int lane = tid & 63, w = tid >> 6;
    const int q = lane & 15, g = lane >> 4;
#pragma unroll
    for (int nt = 0; nt < 2; ++nt) {
        const int n0 = w * 32 + nt * 16;
        const int nrow = n0 + q;
        float4 b1 = *(const float4*)(bi + n0 + g * 4);
        float4 b2 = *(const float4*)(bh + n0 + g * 4);
        f32x4 acc = {b1.x + b2.x, b1.y + b2.y, b1.z + b2.z, b1.w + b2.w};
#pragma unroll
        for (int kb = 0; kb < 2; ++kb) {
            f16x8 a = *(const f16x8*)(Wl + nrow * 128 + (((kb * 4 + g) ^ (nrow & 7)) << 4));
            f16x8 b = *(const f16x8*)(Xl + q * 128 + (((kb * 4 + g) ^ (q & 7)) << 4));
            acc = __builtin_amdgcn_mfma_f32_16x16x32_f16(a, b, acc, 0, 0, 0);
        }
        f16x4 o; o[0] = (f16)acc[0]; o[1] = (f16)acc[1]; o[2] = (f16)acc[2]; o[3] = (f16)acc[3];
        *(f16x4*)(T + (size_t)(v0 + q) * H_ + n0 + g * 4) = o;
    }
}

// ---------------------------------------------------------------------------
// K2: gather xW0[b][s][:] = T[batch[b][s]][:]. Parallel; moves the random-row
// latency off the recurrence's serial chain. 16B per thread, grid-stride.
// ---------------------------------------------------------------------------
__global__ __launch_bounds__(256) void k_gather(
    const int* __restrict__ idx, const f16* __restrict__ T, f16* __restrict__ xw)
{
    const size_t stride = (size_t)gridDim.x * blockDim.x;
    const size_t total = (size_t)B_ * S_ * 32;   // 16B chunks
    for (size_t ci = (size_t)blockIdx.x * blockDim.x + threadIdx.x; ci < total; ci += stride) {
        const size_t r = ci >> 5;
        const int c = (int)(ci & 31);
        const size_t row = (size_t)idx[r];
        *(f16x8*)(xw + r * H_ + c * 8) = *(const f16x8*)(T + row * H_ + c * 8);
    }
}

// ---------------------------------------------------------------------------
// K3/K5-recur: RNN recurrence. 16 WGs x 512 thr (8 waves, 2 waves/SIMD for
// latency hiding). Wave w owns 32 n-cols (2 tt); W_hh slice in regs (64 VGPR).
// h double-buffered in 2x8KB swizzled LDS; one raw barrier per step with
// lgkm-only wait (global loads/stores stay in flight). Per-tt accumulation
// split into two 4-deep MFMA chains. In-place capable (hout may alias xw:
// row t is stored only after row t was consumed; prefetch reads t+2).
// ---------------------------------------------------------------------------
template <bool WRITE_ALL>
__device__ __forceinline__ void rnn_step(
    const int t, const f16* xw, f16* hout, const f16x8 (&wf)[2][8],
    f16x4 (&xv)[2],
    const char* rbuf, char* wbuf,
    const int brow, const int ncol, const int g, const int hrow, const int hswz)
{
    // consume xv (loads issued 2 steps ago)
    f32x4 acc[2], accB[2];
#pragma unroll
    for (int tt = 0; tt < 2; ++tt) {
        acc[tt][0] = (float)xv[tt][0]; acc[tt][1] = (float)xv[tt][1];
        acc[tt][2] = (float)xv[tt][2]; acc[tt][3] = (float)xv[tt][3];
        accB[tt][0] = 0.f; accB[tt][1] = 0.f; accB[tt][2] = 0.f; accB[tt][3] = 0.f;
    }
    // reissue the same registers for step t+2 (anti-dep, no copy)
    if (t + 2 < S_) {
        const size_t rb2 = ((size_t)brow * S_ + t + 2) * H_;
#pragma unroll
        for (int tt = 0; tt < 2; ++tt)
            xv[tt] = *(const f16x4*)(xw + rb2 + ncol + tt * 16 + g * 4);
    }
    // two independent 4-deep MFMA chains per tt (halve dependent latency)
#pragma unroll
    for (int kb = 0; kb < 4; ++kb) {
        f16x8 bf0 = *(const f16x8*)(rbuf + hrow + ((kb * 64 + g * 16) ^ hswz));
        f16x8 bf1 = *(const f16x8*)(rbuf + hrow + (((kb + 4) * 64 + g * 16) ^ hswz));
#pragma unroll
        for (int tt = 0; tt < 2; ++tt) {
            acc[tt]  = __builtin_amdgcn_mfma_f32_16x16x32_f16(wf[tt][kb],     bf0, acc[tt],  0, 0, 0);
            accB[tt] = __builtin_amdgcn_mfma_f32_16x16x32_f16(wf[tt][kb + 4], bf1, accB[tt], 0, 0, 0);
        }
    }
    f16x4 hv[2];
#pragma unroll
    for (int tt = 0; tt < 2; ++tt)
#pragma unroll
        for (int r = 0; r < 4; ++r)
            hv[tt][r] = (f16)fast_tanh(acc[tt][r] + accB[tt][r]);
#pragma unroll
    for (int tt = 0; tt < 2; ++tt) {
        const int nd = ncol + tt * 16 + g * 4;
        *(f16x4*)(wbuf + hrow + ((nd * 2) ^ hswz)) = hv[tt];
    }
    if (WRITE_ALL) {
#pragma unroll
        for (int tt = 0; tt < 2; ++tt)
            *(f16x4*)(hout + ((size_t)brow * S_ + t) * H_ + ncol + tt * 16 + g * 4) = hv[tt];
    } else if (t == S_ - 1) {
#pragma unroll
        for (int tt = 0; tt < 2; ++tt)
            *(f16x4*)(hout + (size_t)brow * H_ + ncol + tt * 16 + g * 4) = hv[tt];
    }
    // LDS-only fence + raw barrier: vmcnt NOT drained (loads/stores fly on)
    asm volatile("s_waitcnt lgkmcnt(0)\n\ts_barrier" ::: "memory");
}

template <bool WRITE_ALL>
__global__ __launch_bounds__(512, 1) void k_recur(
    const f16* xw, const float* __restrict__ Whh, f16* hout)
{
    __shared__ char hbuf[2][16 * 512];  // double-buffered [16 m][256 n f16], swizzled
    const int tid = threadIdx.x, lane = tid & 63, w = tid >> 6;   // w in 0..7
    const int q = lane & 15, g = lane >> 4;
    const int brow = (blockIdx.x << 4) + q;
    const int ncol = w * 32;

    f16x8 wf[2][8];
#pragma unroll
    for (int tt = 0; tt < 2; ++tt) {
        const int n = ncol + tt * 16 + q;
#pragma unroll
        for (int kb = 0; kb < 8; ++kb) {
            float4 a = *(const float4*)(Whh + n * H_ + kb * 32 + g * 8);
            float4 b = *(const float4*)(Whh + n * H_ + kb * 32 + g * 8 + 4);
            wf[tt][kb] = cvt8(a, b);
        }
    }
    {   // h_{-1} = 0 into buf[1] (read buffer of step 0); 512 thr x 16B = 8KB
        f32x4 z = {0.f, 0.f, 0.f, 0.f};
        *(f32x4*)(hbuf[1] + tid * 16) = z;
    }
    const int hswz = (q & 7) << 4;
    const int hrow = q * 512;

    f16x4 xa[2], xb[2];
    {
        const size_t r0 = (size_t)brow * S_ * H_;
#pragma unroll
        for (int tt = 0; tt < 2; ++tt) {
            xa[tt] = *(const f16x4*)(xw + r0 + ncol + tt * 16 + g * 4);
            xb[tt] = *(const f16x4*)(xw + r0 + H_ + ncol + tt * 16 + g * 4);
        }
    }
    __syncthreads();   // once: zero-init + W visible

    for (int t = 0; t < S_; t += 2) {
        rnn_step<WRITE_ALL>(t,     xw, hout, wf, xa, hbuf[1], hbuf[0],
                            brow, ncol, g, hrow, hswz);
        rnn_step<WRITE_ALL>(t + 1, xw, hout, wf, xb, hbuf[0], hbuf[1],
                            brow, ncol, g, hrow, hswz);
    }
}

// ---------------------------------------------------------------------------
// K4: xW1 = h0 @ Wih1^T + (bi+bh), IN PLACE over h0 buffer.
// ---------------------------------------------------------------------------
__global__ __launch_bounds__(512) void k_proj1(
    f16* __restrict__ h0, const float* __restrict__ Wih,
    const float* __restrict__ bi, const float* __restrict__ bh)
{
    __shared__ char Wl[256 * 512];   // 128KB: [256 n][256 f16] swizzled
    __shared__ char Al[32 * 512];    // 16KB: staged h0 rows
    const int tid = threadIdx.x;
    {
        const int n = tid >> 1, k0 = (tid & 1) << 7;
#pragma unroll
        for (int k = k0; k < k0 + 128; k += 8) {
            float4 a = *(const float4*)(Wih + n * H_ + k);
            float4 b = *(const float4*)(Wih + n * H_ + k + 4);
            *(f16x8*)(Wl + n * 512 + (((k >> 3) ^ (n & 7)) << 4)) = cvt8(a, b);
        }
    }
    const int lane = tid & 63, w = tid >> 6;
    const int q = lane & 15, g = lane >> 4;
    for (int rb = blockIdx.x; rb < (B_ * S_) / 32; rb += gridDim.x) {
        const size_t r0 = (size_t)rb * 32;
        __syncthreads();
        {
            const int m = tid >> 4, blk0 = (tid & 15) << 1;
#pragma unroll
            for (int i = 0; i < 2; ++i) {
                const int blk = blk0 + i;
                f16x8 v = *(const f16x8*)(h0 + (r0 + m) * H_ + blk * 8);
                *(f16x8*)(Al + m * 512 + ((blk ^ (m & 7)) << 4)) = v;
            }
        }
        __syncthreads();
        f32x4 acc[2][2];
#pragma unroll
        for (int nt = 0; nt < 2; ++nt) {
            const int nb = w * 32 + nt * 16 + g * 4;
            float4 b1 = *(const float4*)(bi + nb);
            float4 b2 = *(const float4*)(bh + nb);
#pragma unroll
            for (int mt = 0; mt < 2; ++mt) {
                acc[nt][mt][0] = b1.x + b2.x; acc[nt][mt][1] = b1.y + b2.y;
                acc[nt][mt][2] = b1.z + b2.z; acc[nt][mt][3] = b1.w + b2.w;
            }
        }
#pragma unroll
        for (int kb = 0; kb < 8; ++kb) {
            f16x8 af[2], bf[2];
#pragma unroll
            for (int nt = 0; nt < 2; ++nt) {
                const int nrow = w * 32 + nt * 16 + q;
                af[nt] = *(const f16x8*)(Wl + nrow * 512 + (((kb * 4 + g) ^ (nrow & 7)) << 4));
            }
#pragma unroll
            for (int mt = 0; mt < 2; ++mt) {
                const int mrow = mt * 16 + q;
                bf[mt] = *(const f16x8*)(Al + mrow * 512 + (((kb * 4 + g) ^ (mrow & 7)) << 4));
            }
#pragma unroll
            for (int nt = 0; nt < 2; ++nt)
#pragma unroll
                for (int mt = 0; mt < 2; ++mt)
                    acc[nt][mt] = __builtin_amdgcn_mfma_f32_16x16x32_f16(af[nt], bf[mt], acc[nt][mt], 0, 0, 0);
        }
#pragma unroll
        for (int nt = 0; nt < 2; ++nt) {
            const int nb = w * 32 + nt * 16 + g * 4;
#pragma unroll
            for (int mt = 0; mt < 2; ++mt) {
                f16x4 o;
                o[0] = (f16)acc[nt][mt][0]; o[1] = (f16)acc[nt][mt][1];
                o[2] = (f16)acc[nt][mt][2]; o[3] = (f16)acc[nt][mt][3];
                *(f16x4*)(h0 + (r0 + mt * 16 + q) * H_ + nb) = o;
            }
        }
    }
}

// ---------------------------------------------------------------------------
// K6: out[b][v] = sum_k h1[b][k] * Wout[v][k] + bout[v].  fp32 out.
// ---------------------------------------------------------------------------
__global__ __launch_bounds__(512) void k_out(
    const f16* __restrict__ h1, const float* __restrict__ Wout,
    const float* __restrict__ bout, float* __restrict__ out)
{
    __shared__ char Hl[256 * 512];
    const int tid = threadIdx.x;
    {
        const int m = tid >> 1, half = tid & 1;
#pragma unroll
        for (int i = 0; i < 16; ++i) {
            const int blk = half * 16 + i;
            f16x8 v = *(const f16x8*)(h1 + m * H_ + blk * 8);
            *(f16x8*)(Hl + m * 512 + ((blk ^ (m & 7)) << 4)) = v;
        }
    }
    __syncthreads();
    const int lane = tid & 63, w = tid >> 6;
    const int q = lane & 15, g = lane >> 4;
    const int v0 = blockIdx.x * 80;
    f32x4 acc[5][2];
#pragma unroll
    for (int vt = 0; vt < 5; ++vt) {
        float4 bo = *(const float4*)(bout + v0 + vt * 16 + g * 4);
#pragma unroll
        for (int bt = 0; bt < 2; ++bt) {
            acc[vt][bt][0] = bo.x; acc[vt][bt][1] = bo.y;
            acc[vt][bt][2] = bo.z; acc[vt][bt][3] = bo.w;
        }
    }
#pragma unroll
    for (int kb = 0; kb < 8; ++kb) {
        f16x8 bf[2];
#pragma unroll
        for (int bt = 0; bt < 2; ++bt) {
            const int mrow = (w * 2 + bt) * 16 + q;
            bf[bt] = *(const f16x8*)(Hl + mrow * 512 + (((kb * 4 + g) ^ (mrow & 7)) << 4));
        }
#pragma unroll
        for (int vt = 0; vt < 5; ++vt) {
            const size_t vrow = v0 + vt * 16 + q;
            float4 a = *(const float4*)(Wout + vrow * H_ + kb * 32 + g * 8);
            float4 b = *(const float4*)(Wout + vrow * H_ + kb * 32 + g * 8 + 4);
            f16x8 af = cvt8(a, b);
#pragma unroll
            for (int bt = 0; bt < 2; ++bt)
                acc[vt][bt] = __builtin_amdgcn_mfma_f32_16x16x32_f16(af, bf[bt], acc[vt][bt], 0, 0, 0);
        }
    }
#pragma unroll
    for (int vt = 0; vt < 5; ++vt)
#pragma unroll
        for (int bt = 0; bt < 2; ++bt) {
            const int b = (w * 2 + bt) * 16 + q;
            const int v = v0 + vt * 16 + g * 4;
            float4 o = {acc[vt][bt][0], acc[vt][bt][1], acc[vt][bt][2], acc[vt][bt][3]};
            *(float4*)(out + (size_t)b * V_ + v) = o;
        }
}

extern "C" void kernel_launch(void* const* d_in, const int* in_sizes, int n_in,
                              void* d_out, int out_size, void* d_ws, size_t ws_size,
                              hipStream_t stream) {
    (void)in_sizes; (void)n_in; (void)out_size; (void)ws_size;
    const int*   batch = (const int*)  d_in[0];
    const float* feat  = (const float*)d_in[1];
    const float* Wih0  = (const float*)d_in[2];
    const float* Whh0  = (const float*)d_in[3];
    const float* bih0  = (const float*)d_in[4];
    const float* bhh0  = (const float*)d_in[5];
    const float* Wih1  = (const float*)d_in[6];
    const float* Whh1  = (const float*)d_in[7];
    const float* bih1  = (const float*)d_in[8];
    const float* bhh1  = (const float*)d_in[9];
    const float* Wout  = (const float*)d_in[10];
    const float* bout  = (const float*)d_in[11];
    float* out = (float*)d_out;

    f16* T  = (f16*)d_out;     // 25.6MB scratch in d_out; dead before k_out writes
    f16* h0 = (f16*)d_ws;      // 67MB: xW0 -> h0 (in place) -> xW1 (in place)
    f16* h1 = (f16*)((char*)d_ws + (size_t)B_ * S_ * H_ * 2);

    k_vocab_proj<<<dim3(V_ / 16), dim3(512), 0, stream>>>(feat, Wih0, bih0, bhh0, T);
    k_gather<<<dim3(2048), dim3(256), 0, stream>>>(batch, T, h0);
    k_recur<true><<<dim3(16), dim3(512), 0, stream>>>(h0, Whh0, h0);   // in place
    k_proj1<<<dim3(512), dim3(512), 0, stream>>>(h0, Wih1, bih1, bhh1);
    k_recur<false><<<dim3(16), dim3(512), 0, stream>>>(h0, Whh1, h1);
    k_out<<<dim3(625), dim3(512), 0, stream>>>(h1, Wout, bout, out);
}